// Round 10
// baseline (661.418 us; speedup 1.0000x reference)
//
#include <hip/hip_runtime.h>
#include <hip/hip_fp16.h>
#include <math.h>

#define IN_CH 8
#define OUT_CH 64
#define NPW 8   // nodes per wave in dense kernels

__device__ __forceinline__ unsigned short f2h(float f) {   // f32 -> fp16 RNE bits
    return __half_as_ushort(__float2half_rn(f));
}
__device__ __forceinline__ float h2f_lo(unsigned v) {
    return __half2float(__ushort_as_half((unsigned short)(v & 0xFFFFu)));
}
__device__ __forceinline__ float h2f_hi(unsigned v) {
    return __half2float(__ushort_as_half((unsigned short)(v >> 16)));
}
__device__ __forceinline__ float sigmoidf(float v) { return 1.0f / (1.0f + expf(-v)); }

// ---------------- degree histogram ----------------
__global__ void deg_kernel(const int* __restrict__ row, int* __restrict__ deg, int E) {
    int i = blockIdx.x * blockDim.x + threadIdx.x;
    if (i < E) atomicAdd(&deg[row[i]], 1);
}

// ---------------- dinv = deg>0 ? rsqrt(deg) : 0 ----------------
__global__ void dinv_kernel(const int* __restrict__ deg, float* __restrict__ dinv, int N) {
    int i = blockIdx.x * blockDim.x + threadIdx.x;
    if (i < N) {
        int d = deg[i];
        dinv[i] = (d > 0) ? rsqrtf((float)d) : 0.f;
    }
}

// ---------------- single-block exclusive scan: deg -> rowptr, cursor ----------------
__global__ void scan_kernel(const int* __restrict__ deg, int* __restrict__ rowptr,
                            int* __restrict__ cursor, int N) {
    __shared__ int s_wave[17];
    __shared__ int s_running;
    int tid = threadIdx.x;
    int lane = tid & 63, wid = tid >> 6;
    if (tid == 0) s_running = 0;
    __syncthreads();
    for (int base = 0; base < N; base += 1024) {
        int i = base + tid;
        int v = (i < N) ? deg[i] : 0;
        int incl = v;
#pragma unroll
        for (int off = 1; off < 64; off <<= 1) {
            int t = __shfl_up(incl, off, 64);
            if (lane >= off) incl += t;
        }
        if (lane == 63) s_wave[wid] = incl;
        __syncthreads();
        if (wid == 0) {
            int wv = (lane < 16) ? s_wave[lane] : 0;
            int winc = wv;
#pragma unroll
            for (int off = 1; off < 16; off <<= 1) {
                int t = __shfl_up(winc, off, 64);
                if (lane >= off) winc += t;
            }
            if (lane < 16) s_wave[lane] = winc - wv;
            if (lane == 15) s_wave[16] = winc;
        }
        __syncthreads();
        int run = s_running;
        int excl = run + s_wave[wid] + incl - v;
        if (i < N) { rowptr[i] = excl; cursor[i] = excl; }
        __syncthreads();
        if (tid == 0) s_running = run + s_wave[16];
        __syncthreads();
    }
    if (tid == 0) rowptr[N] = s_running;
}

// ---------------- bucket: col-only int32 metadata ----------------
__global__ void bucket_kernel(const int* __restrict__ ei, int* __restrict__ cursor,
                              int* __restrict__ col_s, int E) {
    int e = blockIdx.x * blockDim.x + threadIdx.x;
    if (e >= E) return;
    int r = ei[e];
    int c = ei[E + e];
    int pos = atomicAdd(&cursor[r], 1);
    col_s[pos] = c;
}

// ---------------- prescale+convert: dst_fp16[i] = src[i] * dinv[i>>logd] ----------------
__global__ void xform_kernel(const float* __restrict__ src, unsigned short* __restrict__ dst,
                             const float* __restrict__ dinv, int total4, int logd) {
    int i = blockIdx.x * blockDim.x + threadIdx.x;   // group of 4 elements
    if (i >= total4) return;
    int el = i * 4;
    float s = dinv[el >> logd];
    float4 v = reinterpret_cast<const float4*>(src)[i];
    ushort4 o;
    o.x = f2h(v.x * s); o.y = f2h(v.y * s); o.z = f2h(v.z * s); o.w = f2h(v.w * s);
    reinterpret_cast<ushort4*>(dst)[i] = o;
}

// ---------------- zero row N of the three fp16 buffers ----------------
__global__ void zrow_kernel(unsigned short* xb, unsigned short* Hb, unsigned short* RHb, int N) {
    int t = threadIdx.x;   // 64 threads
    if (t < IN_CH) xb[(size_t)N * IN_CH + t] = 0;
    Hb[(size_t)N * OUT_CH + t] = 0;
    RHb[(size_t)N * OUT_CH + t] = 0;
}

// ---------------- gather DIM=64, fp16 prescaled src, 2 edges/iter ----------------
__global__ void g64_kernel(const int* __restrict__ rowptr, const int* __restrict__ col_s,
                           const float* __restrict__ dinv, const unsigned short* __restrict__ srcb,
                           float* __restrict__ dst, int N) {
    int n = blockIdx.x * (blockDim.x >> 6) + (threadIdx.x >> 6);
    int lane = threadIdx.x & 63;
    int half = lane >> 5;        // 0: even edges, 1: odd edges
    int sl = lane & 31;          // channel pair 2sl, 2sl+1
    if (n >= N) return;
    int beg = rowptr[n], end = rowptr[n + 1];
    const unsigned* src32 = reinterpret_cast<const unsigned*>(srcb);
    float a0 = 0.f, a1 = 0.f;
    for (int base = beg; base < end; base += 64) {
        int cnt = min(end - base, 64);
        int mycol = col_s[base + min(lane, cnt - 1)];   // coalesced 256B
#pragma unroll 4
        for (int e = 0; e < cnt; e += 2) {
            int idx = e + half;
            int c = __shfl(mycol, idx, 64);
            c = (idx < cnt) ? c : N;                    // odd-tail -> zero row
            unsigned v = src32[(c << 5) + sl];          // 2 fp16 channels
            a0 += h2f_lo(v);
            a1 += h2f_hi(v);
        }
    }
    a0 += __shfl_xor(a0, 32, 64);
    a1 += __shfl_xor(a1, 32, 64);
    if (half == 0) {
        float s = -dinv[n];
        reinterpret_cast<float2*>(dst)[(size_t)n * 32 + sl] = make_float2(s * a0, s * a1);
    }
}

// ---------------- gather DIM=8, fp16 prescaled src, 16 edge-groups ----------------
__global__ void g8_kernel(const int* __restrict__ rowptr, const int* __restrict__ col_s,
                          const float* __restrict__ dinv, const unsigned short* __restrict__ srcb,
                          float* __restrict__ dst, int N) {
    int n = blockIdx.x * (blockDim.x >> 6) + (threadIdx.x >> 6);
    int lane = threadIdx.x & 63;
    int g = lane >> 2;           // edge group 0..15
    int o2 = lane & 3;           // channel pair 2*o2, 2*o2+1
    if (n >= N) return;
    int beg = rowptr[n], end = rowptr[n + 1];
    const unsigned* src32 = reinterpret_cast<const unsigned*>(srcb);
    float a0 = 0.f, a1 = 0.f;
    for (int j = beg + g; j < end; j += 16) {
        int c = col_s[j];
        unsigned v = src32[(c << 2) + o2];
        a0 += h2f_lo(v);
        a1 += h2f_hi(v);
    }
#pragma unroll
    for (int m = 4; m < 64; m <<= 1) {
        a0 += __shfl_xor(a0, m, 64);
        a1 += __shfl_xor(a1, m, 64);
    }
    if (lane < 4) {
        float s = -dinv[n];
        reinterpret_cast<float2*>(dst)[(size_t)n * 4 + o2] = make_float2(s * a0, s * a1);
    }
}

// ---------------- gates: NPW nodes/wave, weights loaded once, shfl-broadcast acts ----------
__global__ __launch_bounds__(256) void gates_kernel(
        const float* __restrict__ x, const float* __restrict__ H,
        const float* __restrict__ Lx, const float* __restrict__ LH,
        const float* __restrict__ dinv,
        const float* __restrict__ Wzx, const float* __restrict__ bzx,
        const float* __restrict__ Wzh, const float* __restrict__ bzh,
        const float* __restrict__ Wrx, const float* __restrict__ brx,
        const float* __restrict__ Wrh, const float* __restrict__ brh,
        float* __restrict__ Z, float* __restrict__ RH, unsigned short* __restrict__ RHb, int N) {
    int wid = threadIdx.x >> 6;
    int lane = threadIdx.x & 63;
    int n0 = blockIdx.x * (4 * NPW) + wid * NPW;

    float axl[NPW], hreg[NPW], lhreg[NPW], accZ[NPW], accR[NPW], dv[NPW];
    float bz = bzx[lane] + bzh[lane];
    float br = brx[lane] + brh[lane];
#pragma unroll
    for (int i = 0; i < NPW; ++i) {
        int nn = min(n0 + i, N - 1);
        axl[i]   = (lane < 8) ? x[(size_t)nn * IN_CH + lane]
                 : (lane < 16 ? Lx[(size_t)nn * IN_CH + (lane - 8)] : 0.f);
        hreg[i]  = H[(size_t)nn * OUT_CH + lane];
        lhreg[i] = LH[(size_t)nn * OUT_CH + lane];
        dv[i]    = dinv[nn];
        accZ[i] = bz;
        accR[i] = br;
    }
#pragma unroll
    for (int k = 0; k < IN_CH; ++k) {
        float wz0 = Wzx[k * 64 + lane], wz1 = Wzx[512 + k * 64 + lane];
        float wr0 = Wrx[k * 64 + lane], wr1 = Wrx[512 + k * 64 + lane];
#pragma unroll
        for (int i = 0; i < NPW; ++i) {
            float xv  = __shfl(axl[i], k, 64);
            float lxv = __shfl(axl[i], k + 8, 64);
            accZ[i] = fmaf(xv, wz0, fmaf(lxv, wz1, accZ[i]));
            accR[i] = fmaf(xv, wr0, fmaf(lxv, wr1, accR[i]));
        }
    }
#pragma unroll 4
    for (int k = 0; k < OUT_CH; ++k) {
        float wh0 = Wzh[k * 64 + lane], wh1 = Wzh[4096 + k * 64 + lane];
        float wr0 = Wrh[k * 64 + lane], wr1 = Wrh[4096 + k * 64 + lane];
#pragma unroll
        for (int i = 0; i < NPW; ++i) {
            float hv  = __shfl(hreg[i], k, 64);
            float lhv = __shfl(lhreg[i], k, 64);
            accZ[i] = fmaf(hv, wh0, fmaf(lhv, wh1, accZ[i]));
            accR[i] = fmaf(hv, wr0, fmaf(lhv, wr1, accR[i]));
        }
    }
#pragma unroll
    for (int i = 0; i < NPW; ++i) {
        int n = n0 + i;
        if (n < N) {
            float z = sigmoidf(accZ[i]);
            float r = sigmoidf(accR[i]);
            float rh = r * hreg[i];
            Z[(size_t)n * OUT_CH + lane]  = z;
            RH[(size_t)n * OUT_CH + lane] = rh;
            RHb[(size_t)n * OUT_CH + lane] = f2h(dv[i] * rh);   // prescaled fp16 for gather
        }
    }
}

// ---------------- final: C = tanh(cheb_c), out = Z*H + (1-Z)*C ----------------
__global__ __launch_bounds__(256) void final_kernel(
        const float* __restrict__ x, const float* __restrict__ H,
        const float* __restrict__ Lx, const float* __restrict__ RH,
        const float* __restrict__ LRH,
        const float* __restrict__ Wcx, const float* __restrict__ bcx,
        const float* __restrict__ Wch, const float* __restrict__ bch,
        const float* __restrict__ Z, float* __restrict__ out, int N) {
    int wid = threadIdx.x >> 6;
    int lane = threadIdx.x & 63;
    int n0 = blockIdx.x * (4 * NPW) + wid * NPW;

    float axl[NPW], rhreg[NPW], lrhreg[NPW], accC[NPW];
    float bc = bcx[lane] + bch[lane];
#pragma unroll
    for (int i = 0; i < NPW; ++i) {
        int nn = min(n0 + i, N - 1);
        axl[i]    = (lane < 8) ? x[(size_t)nn * IN_CH + lane]
                  : (lane < 16 ? Lx[(size_t)nn * IN_CH + (lane - 8)] : 0.f);
        rhreg[i]  = RH[(size_t)nn * OUT_CH + lane];
        lrhreg[i] = LRH[(size_t)nn * OUT_CH + lane];
        accC[i] = bc;
    }
#pragma unroll
    for (int k = 0; k < IN_CH; ++k) {
        float wc0 = Wcx[k * 64 + lane], wc1 = Wcx[512 + k * 64 + lane];
#pragma unroll
        for (int i = 0; i < NPW; ++i) {
            float xv  = __shfl(axl[i], k, 64);
            float lxv = __shfl(axl[i], k + 8, 64);
            accC[i] = fmaf(xv, wc0, fmaf(lxv, wc1, accC[i]));
        }
    }
#pragma unroll 4
    for (int k = 0; k < OUT_CH; ++k) {
        float wh0 = Wch[k * 64 + lane], wh1 = Wch[4096 + k * 64 + lane];
#pragma unroll
        for (int i = 0; i < NPW; ++i) {
            float rv  = __shfl(rhreg[i], k, 64);
            float lrv = __shfl(lrhreg[i], k, 64);
            accC[i] = fmaf(rv, wh0, fmaf(lrv, wh1, accC[i]));
        }
    }
#pragma unroll
    for (int i = 0; i < NPW; ++i) {
        int n = n0 + i;
        if (n < N) {
            float c = tanhf(accC[i]);
            float z = Z[(size_t)n * OUT_CH + lane];
            float h = H[(size_t)n * OUT_CH + lane];
            out[(size_t)n * OUT_CH + lane] = z * h + (1.0f - z) * c;
        }
    }
}

extern "C" void kernel_launch(void* const* d_in, const int* in_sizes, int n_in,
                              void* d_out, int out_size, void* d_ws, size_t ws_size,
                              hipStream_t stream) {
    const float* x   = (const float*)d_in[0];
    const float* H   = (const float*)d_in[1];
    const int*   ei  = (const int*)d_in[2];
    const float* Wzx = (const float*)d_in[3];
    const float* bzx = (const float*)d_in[4];
    const float* Wzh = (const float*)d_in[5];
    const float* bzh = (const float*)d_in[6];
    const float* Wrx = (const float*)d_in[7];
    const float* brx = (const float*)d_in[8];
    const float* Wrh = (const float*)d_in[9];
    const float* brh = (const float*)d_in[10];
    const float* Wcx = (const float*)d_in[11];
    const float* bcx = (const float*)d_in[12];
    const float* Wch = (const float*)d_in[13];
    const float* bch = (const float*)d_in[14];

    const int N = in_sizes[0] / IN_CH;
    const int E = in_sizes[2] / 2;

    // workspace layout (4B words):
    int*   deg    = (int*)d_ws;                                   // N (aliased cursor)
    float* dinv   = (float*)(deg + N);                            // N
    int*   rowptr = (int*)(dinv + N);                             // N+2
    int*   col_s  = rowptr + (N + 2);                             // E int32
    unsigned short* xb  = (unsigned short*)(col_s + E);           // (N+1)*8 fp16
    unsigned short* Hb  = xb + (size_t)(N + 1) * IN_CH;           // (N+1)*64 fp16
    unsigned short* RHb = Hb + (size_t)(N + 1) * OUT_CH;          // (N+1)*64 fp16
    float* Lx  = (float*)(RHb + (size_t)(N + 1) * OUT_CH);        // 8N f32
    float* LH  = Lx + (size_t)N * IN_CH;                          // 64N (reused as LRH)
    float* Z   = LH + (size_t)N * OUT_CH;                         // 64N
    float* RH  = Z  + (size_t)N * OUT_CH;                         // 64N
    float* LRH = LH;
    int*   cursor = deg;

    hipMemsetAsync(deg, 0, (size_t)N * sizeof(int), stream);

    const int tb = 256;
    deg_kernel<<<(E + tb - 1) / tb, tb, 0, stream>>>(ei, deg, E);
    dinv_kernel<<<(N + tb - 1) / tb, tb, 0, stream>>>(deg, dinv, N);
    scan_kernel<<<1, 1024, 0, stream>>>(deg, rowptr, cursor, N);
    bucket_kernel<<<(E + tb - 1) / tb, tb, 0, stream>>>(ei, cursor, col_s, E);

    // prescaled fp16 sources
    {
        int t4 = N * OUT_CH / 4;
        xform_kernel<<<(t4 + tb - 1) / tb, tb, 0, stream>>>(H, Hb, dinv, t4, 6);
        t4 = N * IN_CH / 4;
        xform_kernel<<<(t4 + tb - 1) / tb, tb, 0, stream>>>(x, xb, dinv, t4, 3);
        zrow_kernel<<<1, 64, 0, stream>>>(xb, Hb, RHb, N);
    }

    const int nblk4 = (N + 3) / 4;                    // gathers: 1 node/wave
    const int nblkD = (N + 4 * NPW - 1) / (4 * NPW);  // dense: NPW nodes/wave

    g8_kernel <<<nblk4, tb, 0, stream>>>(rowptr, col_s, dinv, xb, Lx, N);
    g64_kernel<<<nblk4, tb, 0, stream>>>(rowptr, col_s, dinv, Hb, LH, N);

    gates_kernel<<<nblkD, tb, 0, stream>>>(x, H, Lx, LH, dinv, Wzx, bzx, Wzh, bzh,
                                           Wrx, brx, Wrh, brh, Z, RH, RHb, N);

    g64_kernel<<<nblk4, tb, 0, stream>>>(rowptr, col_s, dinv, RHb, LRH, N);

    final_kernel<<<nblkD, tb, 0, stream>>>(x, H, Lx, RH, LRH, Wcx, bcx, Wch, bch,
                                           Z, (float*)d_out, N);
}

// Round 11
// 612.347 us; speedup vs baseline: 1.0801x; 1.0801x over previous
//
#include <hip/hip_runtime.h>
#include <hip/hip_fp16.h>
#include <math.h>

#define IN_CH 8
#define OUT_CH 64
#define NPW 8   // nodes per wave in dense kernels

__device__ __forceinline__ unsigned short f2h(float f) {   // f32 -> fp16 RNE bits
    return __half_as_ushort(__float2half_rn(f));
}
__device__ __forceinline__ float h2f_lo(unsigned v) {
    return __half2float(__ushort_as_half((unsigned short)(v & 0xFFFFu)));
}
__device__ __forceinline__ float h2f_hi(unsigned v) {
    return __half2float(__ushort_as_half((unsigned short)(v >> 16)));
}
__device__ __forceinline__ float sigmoidf(float v) { return 1.0f / (1.0f + expf(-v)); }

// ---------------- degree histogram, XCD-partitioned by destination row ----------------
// block b serves row partition p = b&7 (== its XCD under round-robin dispatch);
// scans all edges, keeps rows in [p*RPP, (p+1)*RPP) -> deg writes stay in one XCD's L2.
__global__ void degP_kernel(const int* __restrict__ row, int* __restrict__ deg,
                            int E, int RPP) {
    int p = blockIdx.x & 7;
    int sub = blockIdx.x >> 3;
    int nsub = gridDim.x >> 3;
    int lo = p * RPP, hi = lo + RPP;
    for (int e = sub * blockDim.x + threadIdx.x; e < E; e += nsub * blockDim.x) {
        int r = row[e];
        if (r >= lo && r < hi) atomicAdd(&deg[r], 1);
    }
}

// ---------------- dinv = deg>0 ? rsqrt(deg) : 0 ----------------
__global__ void dinv_kernel(const int* __restrict__ deg, float* __restrict__ dinv, int N) {
    int i = blockIdx.x * blockDim.x + threadIdx.x;
    if (i < N) {
        int d = deg[i];
        dinv[i] = (d > 0) ? rsqrtf((float)d) : 0.f;
    }
}

// ---------------- single-block exclusive scan: deg -> rowptr, cursor ----------------
__global__ void scan_kernel(const int* __restrict__ deg, int* __restrict__ rowptr,
                            int* __restrict__ cursor, int N) {
    __shared__ int s_wave[17];
    __shared__ int s_running;
    int tid = threadIdx.x;
    int lane = tid & 63, wid = tid >> 6;
    if (tid == 0) s_running = 0;
    __syncthreads();
    for (int base = 0; base < N; base += 1024) {
        int i = base + tid;
        int v = (i < N) ? deg[i] : 0;
        int incl = v;
#pragma unroll
        for (int off = 1; off < 64; off <<= 1) {
            int t = __shfl_up(incl, off, 64);
            if (lane >= off) incl += t;
        }
        if (lane == 63) s_wave[wid] = incl;
        __syncthreads();
        if (wid == 0) {
            int wv = (lane < 16) ? s_wave[lane] : 0;
            int winc = wv;
#pragma unroll
            for (int off = 1; off < 16; off <<= 1) {
                int t = __shfl_up(winc, off, 64);
                if (lane >= off) winc += t;
            }
            if (lane < 16) s_wave[lane] = winc - wv;
            if (lane == 15) s_wave[16] = winc;
        }
        __syncthreads();
        int run = s_running;
        int excl = run + s_wave[wid] + incl - v;
        if (i < N) { rowptr[i] = excl; cursor[i] = excl; }
        __syncthreads();
        if (tid == 0) s_running = run + s_wave[16];
        __syncthreads();
    }
    if (tid == 0) rowptr[N] = s_running;
}

// ---------------- bucket, XCD-partitioned: col_s segment for partition p is contiguous --
__global__ void bucketP_kernel(const int* __restrict__ ei, int* __restrict__ cursor,
                               int* __restrict__ col_s, int E, int RPP) {
    int p = blockIdx.x & 7;
    int sub = blockIdx.x >> 3;
    int nsub = gridDim.x >> 3;
    int lo = p * RPP, hi = lo + RPP;
    for (int e = sub * blockDim.x + threadIdx.x; e < E; e += nsub * blockDim.x) {
        int r = ei[e];
        if (r >= lo && r < hi) {
            int c = ei[E + e];
            int pos = atomicAdd(&cursor[r], 1);
            col_s[pos] = c;
        }
    }
}

// ---------------- prescale+convert: dst_fp16[i] = src[i] * dinv[i>>logd] ----------------
__global__ void xform_kernel(const float* __restrict__ src, unsigned short* __restrict__ dst,
                             const float* __restrict__ dinv, int total4, int logd) {
    int i = blockIdx.x * blockDim.x + threadIdx.x;   // group of 4 elements
    if (i >= total4) return;
    int el = i * 4;
    float s = dinv[el >> logd];
    float4 v = reinterpret_cast<const float4*>(src)[i];
    ushort4 o;
    o.x = f2h(v.x * s); o.y = f2h(v.y * s); o.z = f2h(v.z * s); o.w = f2h(v.w * s);
    reinterpret_cast<ushort4*>(dst)[i] = o;
}

// ---------------- zero row N of the three fp16 buffers ----------------
__global__ void zrow_kernel(unsigned short* xb, unsigned short* Hb, unsigned short* RHb, int N) {
    int t = threadIdx.x;   // 64 threads
    if (t < IN_CH) xb[(size_t)N * IN_CH + t] = 0;
    Hb[(size_t)N * OUT_CH + t] = 0;
    RHb[(size_t)N * OUT_CH + t] = 0;
}

// ---------------- gather DIM=64, fp16 prescaled src, 2 edges/iter ----------------
__global__ void g64_kernel(const int* __restrict__ rowptr, const int* __restrict__ col_s,
                           const float* __restrict__ dinv, const unsigned short* __restrict__ srcb,
                           float* __restrict__ dst, int N) {
    int n = blockIdx.x * (blockDim.x >> 6) + (threadIdx.x >> 6);
    int lane = threadIdx.x & 63;
    int half = lane >> 5;        // 0: even edges, 1: odd edges
    int sl = lane & 31;          // channel pair 2sl, 2sl+1
    if (n >= N) return;
    int beg = rowptr[n], end = rowptr[n + 1];
    const unsigned* src32 = reinterpret_cast<const unsigned*>(srcb);
    float a0 = 0.f, a1 = 0.f;
    for (int base = beg; base < end; base += 64) {
        int cnt = min(end - base, 64);
        int mycol = col_s[base + min(lane, cnt - 1)];   // coalesced 256B
#pragma unroll 4
        for (int e = 0; e < cnt; e += 2) {
            int idx = e + half;
            int c = __shfl(mycol, idx, 64);
            c = (idx < cnt) ? c : N;                    // odd-tail -> zero row
            unsigned v = src32[(c << 5) + sl];          // 2 fp16 channels
            a0 += h2f_lo(v);
            a1 += h2f_hi(v);
        }
    }
    a0 += __shfl_xor(a0, 32, 64);
    a1 += __shfl_xor(a1, 32, 64);
    if (half == 0) {
        float s = -dinv[n];
        reinterpret_cast<float2*>(dst)[(size_t)n * 32 + sl] = make_float2(s * a0, s * a1);
    }
}

// ---------------- gather DIM=8, fp16 prescaled src, 16 edge-groups ----------------
__global__ void g8_kernel(const int* __restrict__ rowptr, const int* __restrict__ col_s,
                          const float* __restrict__ dinv, const unsigned short* __restrict__ srcb,
                          float* __restrict__ dst, int N) {
    int n = blockIdx.x * (blockDim.x >> 6) + (threadIdx.x >> 6);
    int lane = threadIdx.x & 63;
    int g = lane >> 2;           // edge group 0..15
    int o2 = lane & 3;           // channel pair 2*o2, 2*o2+1
    if (n >= N) return;
    int beg = rowptr[n], end = rowptr[n + 1];
    const unsigned* src32 = reinterpret_cast<const unsigned*>(srcb);
    float a0 = 0.f, a1 = 0.f;
    for (int j = beg + g; j < end; j += 16) {
        int c = col_s[j];
        unsigned v = src32[(c << 2) + o2];
        a0 += h2f_lo(v);
        a1 += h2f_hi(v);
    }
#pragma unroll
    for (int m = 4; m < 64; m <<= 1) {
        a0 += __shfl_xor(a0, m, 64);
        a1 += __shfl_xor(a1, m, 64);
    }
    if (lane < 4) {
        float s = -dinv[n];
        reinterpret_cast<float2*>(dst)[(size_t)n * 4 + o2] = make_float2(s * a0, s * a1);
    }
}

// ---------------- gates: NPW nodes/wave, weights loaded once, shfl-broadcast acts ----------
__global__ __launch_bounds__(256) void gates_kernel(
        const float* __restrict__ x, const float* __restrict__ H,
        const float* __restrict__ Lx, const float* __restrict__ LH,
        const float* __restrict__ dinv,
        const float* __restrict__ Wzx, const float* __restrict__ bzx,
        const float* __restrict__ Wzh, const float* __restrict__ bzh,
        const float* __restrict__ Wrx, const float* __restrict__ brx,
        const float* __restrict__ Wrh, const float* __restrict__ brh,
        float* __restrict__ Z, float* __restrict__ RH, unsigned short* __restrict__ RHb, int N) {
    int wid = threadIdx.x >> 6;
    int lane = threadIdx.x & 63;
    int n0 = blockIdx.x * (4 * NPW) + wid * NPW;

    float axl[NPW], hreg[NPW], lhreg[NPW], accZ[NPW], accR[NPW], dv[NPW];
    float bz = bzx[lane] + bzh[lane];
    float br = brx[lane] + brh[lane];
#pragma unroll
    for (int i = 0; i < NPW; ++i) {
        int nn = min(n0 + i, N - 1);
        axl[i]   = (lane < 8) ? x[(size_t)nn * IN_CH + lane]
                 : (lane < 16 ? Lx[(size_t)nn * IN_CH + (lane - 8)] : 0.f);
        hreg[i]  = H[(size_t)nn * OUT_CH + lane];
        lhreg[i] = LH[(size_t)nn * OUT_CH + lane];
        dv[i]    = dinv[nn];
        accZ[i] = bz;
        accR[i] = br;
    }
#pragma unroll
    for (int k = 0; k < IN_CH; ++k) {
        float wz0 = Wzx[k * 64 + lane], wz1 = Wzx[512 + k * 64 + lane];
        float wr0 = Wrx[k * 64 + lane], wr1 = Wrx[512 + k * 64 + lane];
#pragma unroll
        for (int i = 0; i < NPW; ++i) {
            float xv  = __shfl(axl[i], k, 64);
            float lxv = __shfl(axl[i], k + 8, 64);
            accZ[i] = fmaf(xv, wz0, fmaf(lxv, wz1, accZ[i]));
            accR[i] = fmaf(xv, wr0, fmaf(lxv, wr1, accR[i]));
        }
    }
#pragma unroll 4
    for (int k = 0; k < OUT_CH; ++k) {
        float wh0 = Wzh[k * 64 + lane], wh1 = Wzh[4096 + k * 64 + lane];
        float wr0 = Wrh[k * 64 + lane], wr1 = Wrh[4096 + k * 64 + lane];
#pragma unroll
        for (int i = 0; i < NPW; ++i) {
            float hv  = __shfl(hreg[i], k, 64);
            float lhv = __shfl(lhreg[i], k, 64);
            accZ[i] = fmaf(hv, wh0, fmaf(lhv, wh1, accZ[i]));
            accR[i] = fmaf(hv, wr0, fmaf(lhv, wr1, accR[i]));
        }
    }
#pragma unroll
    for (int i = 0; i < NPW; ++i) {
        int n = n0 + i;
        if (n < N) {
            float z = sigmoidf(accZ[i]);
            float r = sigmoidf(accR[i]);
            float rh = r * hreg[i];
            Z[(size_t)n * OUT_CH + lane]  = z;
            RH[(size_t)n * OUT_CH + lane] = rh;
            RHb[(size_t)n * OUT_CH + lane] = f2h(dv[i] * rh);   // prescaled fp16 for gather
        }
    }
}

// ---------------- final: C = tanh(cheb_c), out = Z*H + (1-Z)*C ----------------
__global__ __launch_bounds__(256) void final_kernel(
        const float* __restrict__ x, const float* __restrict__ H,
        const float* __restrict__ Lx, const float* __restrict__ RH,
        const float* __restrict__ LRH,
        const float* __restrict__ Wcx, const float* __restrict__ bcx,
        const float* __restrict__ Wch, const float* __restrict__ bch,
        const float* __restrict__ Z, float* __restrict__ out, int N) {
    int wid = threadIdx.x >> 6;
    int lane = threadIdx.x & 63;
    int n0 = blockIdx.x * (4 * NPW) + wid * NPW;

    float axl[NPW], rhreg[NPW], lrhreg[NPW], accC[NPW];
    float bc = bcx[lane] + bch[lane];
#pragma unroll
    for (int i = 0; i < NPW; ++i) {
        int nn = min(n0 + i, N - 1);
        axl[i]    = (lane < 8) ? x[(size_t)nn * IN_CH + lane]
                  : (lane < 16 ? Lx[(size_t)nn * IN_CH + (lane - 8)] : 0.f);
        rhreg[i]  = RH[(size_t)nn * OUT_CH + lane];
        lrhreg[i] = LRH[(size_t)nn * OUT_CH + lane];
        accC[i] = bc;
    }
#pragma unroll
    for (int k = 0; k < IN_CH; ++k) {
        float wc0 = Wcx[k * 64 + lane], wc1 = Wcx[512 + k * 64 + lane];
#pragma unroll
        for (int i = 0; i < NPW; ++i) {
            float xv  = __shfl(axl[i], k, 64);
            float lxv = __shfl(axl[i], k + 8, 64);
            accC[i] = fmaf(xv, wc0, fmaf(lxv, wc1, accC[i]));
        }
    }
#pragma unroll 4
    for (int k = 0; k < OUT_CH; ++k) {
        float wh0 = Wch[k * 64 + lane], wh1 = Wch[4096 + k * 64 + lane];
#pragma unroll
        for (int i = 0; i < NPW; ++i) {
            float rv  = __shfl(rhreg[i], k, 64);
            float lrv = __shfl(lrhreg[i], k, 64);
            accC[i] = fmaf(rv, wh0, fmaf(lrv, wh1, accC[i]));
        }
    }
#pragma unroll
    for (int i = 0; i < NPW; ++i) {
        int n = n0 + i;
        if (n < N) {
            float c = tanhf(accC[i]);
            float z = Z[(size_t)n * OUT_CH + lane];
            float h = H[(size_t)n * OUT_CH + lane];
            out[(size_t)n * OUT_CH + lane] = z * h + (1.0f - z) * c;
        }
    }
}

extern "C" void kernel_launch(void* const* d_in, const int* in_sizes, int n_in,
                              void* d_out, int out_size, void* d_ws, size_t ws_size,
                              hipStream_t stream) {
    const float* x   = (const float*)d_in[0];
    const float* H   = (const float*)d_in[1];
    const int*   ei  = (const int*)d_in[2];
    const float* Wzx = (const float*)d_in[3];
    const float* bzx = (const float*)d_in[4];
    const float* Wzh = (const float*)d_in[5];
    const float* bzh = (const float*)d_in[6];
    const float* Wrx = (const float*)d_in[7];
    const float* brx = (const float*)d_in[8];
    const float* Wrh = (const float*)d_in[9];
    const float* brh = (const float*)d_in[10];
    const float* Wcx = (const float*)d_in[11];
    const float* bcx = (const float*)d_in[12];
    const float* Wch = (const float*)d_in[13];
    const float* bch = (const float*)d_in[14];

    const int N = in_sizes[0] / IN_CH;
    const int E = in_sizes[2] / 2;
    const int RPP = (N + 7) / 8;   // rows per XCD partition

    // workspace layout (4B words):
    int*   deg    = (int*)d_ws;                                   // N (aliased cursor)
    float* dinv   = (float*)(deg + N);                            // N
    int*   rowptr = (int*)(dinv + N);                             // N+2
    int*   col_s  = rowptr + (N + 2);                             // E int32
    unsigned short* xb  = (unsigned short*)(col_s + E);           // (N+1)*8 fp16
    unsigned short* Hb  = xb + (size_t)(N + 1) * IN_CH;           // (N+1)*64 fp16
    unsigned short* RHb = Hb + (size_t)(N + 1) * OUT_CH;          // (N+1)*64 fp16
    float* Lx  = (float*)(RHb + (size_t)(N + 1) * OUT_CH);        // 8N f32
    float* LH  = Lx + (size_t)N * IN_CH;                          // 64N (reused as LRH)
    float* Z   = LH + (size_t)N * OUT_CH;                         // 64N
    float* RH  = Z  + (size_t)N * OUT_CH;                         // 64N
    float* LRH = LH;
    int*   cursor = deg;

    hipMemsetAsync(deg, 0, (size_t)N * sizeof(int), stream);

    const int tb = 256;
    const int nblkP = 8 * 128;   // 8 partitions x 128 blocks each

    degP_kernel<<<nblkP, tb, 0, stream>>>(ei, deg, E, RPP);
    dinv_kernel<<<(N + tb - 1) / tb, tb, 0, stream>>>(deg, dinv, N);
    scan_kernel<<<1, 1024, 0, stream>>>(deg, rowptr, cursor, N);
    bucketP_kernel<<<nblkP, tb, 0, stream>>>(ei, cursor, col_s, E, RPP);

    // prescaled fp16 sources
    {
        int t4 = N * OUT_CH / 4;
        xform_kernel<<<(t4 + tb - 1) / tb, tb, 0, stream>>>(H, Hb, dinv, t4, 6);
        t4 = N * IN_CH / 4;
        xform_kernel<<<(t4 + tb - 1) / tb, tb, 0, stream>>>(x, xb, dinv, t4, 3);
        zrow_kernel<<<1, 64, 0, stream>>>(xb, Hb, RHb, N);
    }

    const int nblk4 = (N + 3) / 4;                    // gathers: 1 node/wave
    const int nblkD = (N + 4 * NPW - 1) / (4 * NPW);  // dense: NPW nodes/wave

    g8_kernel <<<nblk4, tb, 0, stream>>>(rowptr, col_s, dinv, xb, Lx, N);
    g64_kernel<<<nblk4, tb, 0, stream>>>(rowptr, col_s, dinv, Hb, LH, N);

    gates_kernel<<<nblkD, tb, 0, stream>>>(x, H, Lx, LH, dinv, Wzx, bzx, Wzh, bzh,
                                           Wrx, brx, Wrh, brh, Z, RH, RHb, N);

    g64_kernel<<<nblk4, tb, 0, stream>>>(rowptr, col_s, dinv, RHb, LRH, N);

    final_kernel<<<nblkD, tb, 0, stream>>>(x, H, Lx, RH, LRH, Wcx, bcx, Wch, bch,
                                           Z, (float*)d_out, N);
}